// Round 2
// 478.154 us; speedup vs baseline: 1.0338x; 1.0338x over previous
//
#include <hip/hip_runtime.h>
#include <math.h>

#define B_    128
#define CIN   128
#define TIN   2500
#define COUT  64
#define KW    27
#define TOUT  625
#define TPAD  640   // padded t extent for bf16 q/k/v planes
#define CTT   32    // conv t-tile
#define GROWS 152   // conv staging rows (span 4*31+27=151, pad to 152)

typedef __bf16 bf16x8 __attribute__((ext_vector_type(8)));
typedef float  f32x4  __attribute__((ext_vector_type(4)));

__device__ __forceinline__ unsigned short f32_to_bf16_rne(float v) {
    unsigned u = __float_as_uint(v);
    u += 0x7FFFu + ((u >> 16) & 1u);
    return (unsigned short)(u >> 16);
}

__device__ __forceinline__ f32x4 mfma_bf16(bf16x8 a, bf16x8 b, f32x4 c) {
    return __builtin_amdgcn_mfma_f32_16x16x32_bf16(a, b, c, 0, 0, 0);
}

// ---------------------------------------------------------------------------
// K0: alpha[o] = mean|w|; packed sign bits:
//     sgn2[(kk*4+kg)*64 + o] = u32, byte cs holds bits j for c = cs*32+kg*8+j
// ---------------------------------------------------------------------------
__global__ void binarize_kernel(const float* __restrict__ w,
                                unsigned* __restrict__ sgn2,
                                float* __restrict__ alpha_out) {
    int o = blockIdx.x, tid = threadIdx.x;
    __shared__ float red[256];
    const float* wo_ = w + (size_t)o * (CIN * KW);
    float s = 0.f;
    for (int idx = tid; idx < CIN * KW; idx += 256) s += fabsf(wo_[idx]);
    red[tid] = s;
    __syncthreads();
    for (int st = 128; st > 0; st >>= 1) {
        if (tid < st) red[tid] += red[tid + st];
        __syncthreads();
    }
    if (tid == 0) alpha_out[o] = red[0] / (float)(CIN * KW);

    for (int t = tid; t < KW * 4; t += 256) {
        int kk = t >> 2, kg = t & 3;
        unsigned u = 0;
#pragma unroll
        for (int cs = 0; cs < 4; cs++) {
#pragma unroll
            for (int j = 0; j < 8; j++) {
                int c = cs * 32 + kg * 8 + j;
                float v = wo_[c * KW + kk];
                unsigned bit = (v > 0.f) ? 0u : 1u;
                u |= bit << (cs * 8 + j);
            }
        }
        sgn2[(kk * 4 + kg) * 64 + o] = u;
    }
}

// ---------------------------------------------------------------------------
// K0b: blocks 0-2: transpose wq/wk/wv -> wT[c][o]; block 3: wo -> bf16 hi/lo
//      [o][c]; block 4: fold alpha+bias+BN into scA/scB
// ---------------------------------------------------------------------------
__global__ void transpose_w_kernel(const float* __restrict__ wq, const float* __restrict__ wk,
                                   const float* __restrict__ wv, const float* __restrict__ wo,
                                   const float* __restrict__ conv_b, const float* __restrict__ gamma_,
                                   const float* __restrict__ beta_, const float* __restrict__ mean_,
                                   const float* __restrict__ var_, const float* __restrict__ alpha_,
                                   float* __restrict__ dstT,
                                   unsigned short* __restrict__ wo_h, unsigned short* __restrict__ wo_l,
                                   float* __restrict__ scA, float* __restrict__ scB) {
    if (blockIdx.x < 3) {
        const float* srcs[3] = {wq, wk, wv};
        const float* src = srcs[blockIdx.x];
        float* dst = dstT + (size_t)blockIdx.x * 4096;
        for (int idx = threadIdx.x; idx < 4096; idx += 256) {
            int o = idx >> 6, c = idx & 63;
            dst[c * 64 + o] = src[idx];
        }
    } else if (blockIdx.x == 3) {
        for (int idx = threadIdx.x; idx < 4096; idx += 256) {
            float v = wo[idx];
            unsigned short h = f32_to_bf16_rne(v);
            float hf = __uint_as_float((unsigned)h << 16);
            wo_h[idx] = h;
            wo_l[idx] = f32_to_bf16_rne(v - hf);
        }
    } else {
        int o = threadIdx.x;
        if (o < 64) {
            float inv = rsqrtf(var_[o] + 1e-5f);
            float G = gamma_[o] * inv;
            scA[o] = alpha_[o] * G;
            scB[o] = (conv_b[o] - mean_[o]) * G + beta_[o];
        }
    }
}

// ---------------------------------------------------------------------------
// K1: binarized conv1d via bf16 MFMA + BN/ELU -> y.
//   Sign expansion via 16-entry LDS nibble-LUT (2x ds_read_b64 per fragment,
//   provably conflict-free: 16 entries x 8B map 1:1 onto the 32 banks; same-
//   entry reads broadcast). Replaces ~32 VALU ops/fragment.
// ---------------------------------------------------------------------------
__global__ __launch_bounds__(256, 4) void conv_kernel(
    const float* __restrict__ x, const unsigned* __restrict__ sgn2,
    const float* __restrict__ scA, const float* __restrict__ scB,
    float* __restrict__ y_out)
{
    __shared__ __align__(16) unsigned short xhi[GROWS * 128];  // 38912 B
    __shared__ __align__(16) unsigned long long sgnlut[16];    // 128 B

    int b = blockIdx.y;
    int t0 = blockIdx.x * CTT;
    int tid = threadIdx.x;

    // ---- nibble -> 4x bf16(+-1.0) LUT (bit=1 => -1.0) ----
    if (tid < 16) {
        unsigned long long e = 0;
#pragma unroll
        for (int j = 0; j < 4; ++j) {
            unsigned long long h = ((tid >> j) & 1) ? 0xBF80ull : 0x3F80ull;
            e |= h << (16 * j);
        }
        sgnlut[tid] = e;
    }

    // ---- stage x (hi bf16, RNE): task = (c8, gl); 8 loads -> one b128 ----
    const float* xb = x + (size_t)b * CIN * TIN;
    int gbase = 4 * t0 - 13;
    for (int task = tid; task < 16 * GROWS; task += 256) {
        int c8 = task / GROWS, gl = task - c8 * GROWS;
        int g = gbase + gl;
        bool valid = (gl < 151) && ((unsigned)g < (unsigned)TIN);
        float vs[8];
#pragma unroll
        for (int j = 0; j < 8; j++)
            vs[j] = valid ? xb[(size_t)(c8 * 8 + j) * TIN + g] : 0.f;
        union { unsigned u[4]; uint4 q; } H;
#pragma unroll
        for (int j = 0; j < 4; j++) {
            unsigned short h0 = f32_to_bf16_rne(vs[2 * j]);
            unsigned short h1 = f32_to_bf16_rne(vs[2 * j + 1]);
            H.u[j] = (unsigned)h0 | ((unsigned)h1 << 16);
        }
        int c8p = c8 ^ ((gl >> 2) & 15);
        *(uint4*)(xhi + gl * 128 + c8p * 8) = H.q;
    }
    __syncthreads();

    // ---- MFMA K-loop ----
    int wave = tid >> 6, lane = tid & 63;
    int o0 = wave * 16;             // 16-o slice per wave
    int n = lane & 15, kg = lane >> 4;

    f32x4 acc0 = {0.f, 0.f, 0.f, 0.f};   // t-tile 0 (t0..t0+15)
    f32x4 acc1 = {0.f, 0.f, 0.f, 0.f};   // t-tile 1 (t0+16..t0+31)

    const unsigned* sgb = sgn2 + (size_t)kg * 64 + o0 + n;
    unsigned sa = sgb[0];

#pragma unroll 1
    for (int kk = 0; kk < KW; ++kk) {
        unsigned na = 0;
        if (kk < KW - 1) na = sgb[(kk + 1) * 256];   // prefetch (L1-hot)
        int gl = 4 * n + kk;                          // t-tile 0 row
        int rot = (gl >> 2) & 15;                     // same rot for gl+64
        const unsigned short* xr0 = xhi + gl * 128;
        const unsigned short* xr1 = xr0 + 8192;       // +64 rows
#pragma unroll
        for (int cs = 0; cs < 4; ++cs) {
            int c8p = (cs * 4 + kg) ^ rot;
            bf16x8 b0 = *(const bf16x8*)(xr0 + c8p * 8);
            bf16x8 b1 = *(const bf16x8*)(xr1 + c8p * 8);
            unsigned byte = (sa >> (8 * cs)) & 0xFFu;
            union { unsigned long long u[2]; bf16x8 v; } A;
            A.u[0] = sgnlut[byte & 15u];
            A.u[1] = sgnlut[byte >> 4];
            acc0 = mfma_bf16(A.v, b0, acc0);
            acc1 = mfma_bf16(A.v, b1, acc1);
        }
        sa = na;
    }

    // ---- epilogue: C col = lane&15 (t), row = quad*4+r (o-within-16) ----
    int quad = lane >> 4, col = lane & 15;
#pragma unroll
    for (int tt = 0; tt < 2; ++tt) {
        int t_g = t0 + tt * 16 + col;
        if (t_g < TOUT) {
            f32x4 a = tt ? acc1 : acc0;
#pragma unroll
            for (int r = 0; r < 4; ++r) {
                int o = o0 + quad * 4 + r;
                float s = a[r] * scA[o] + scB[o];
                float yv = s > 0.f ? s : expm1f(s);
                y_out[((size_t)b * COUT + o) * TOUT + t_g] = yv;
            }
        }
    }
}

// ---------------------------------------------------------------------------
// K1b: projections q=wq@spike(y), k=wk@spike(y), v=wv@y.
//   v2: ALL weights staged in LDS (48 KB) + 64-t y tile (18.4 KB): the inner
//   loop is pure LDS (broadcast y via float4, stride-1 w) -> no per-thread
//   global loads (R4/R5 pathology). Thread (oo, tq): 16 t each.
// ---------------------------------------------------------------------------
__global__ __launch_bounds__(256, 2) void proj_kernel(
    const float* __restrict__ y, const float* __restrict__ wqT,
    const float* __restrict__ wkT, const float* __restrict__ wvT,
    unsigned short* __restrict__ q_h, unsigned short* __restrict__ k_h,
    unsigned short* __restrict__ vT_h)
{
    __shared__ float w_sh[3 * 4096];          // 49152 B: wqT | wkT | wvT ([c][o])
    __shared__ __align__(16) float y_sh[64 * 72];  // 18432 B, stride 72
    int b = blockIdx.y, t0 = blockIdx.x * 64, tid = threadIdx.x;

    for (int i = tid; i < 4096; i += 256) {
        w_sh[i]         = wqT[i];
        w_sh[4096 + i]  = wkT[i];
        w_sh[8192 + i]  = wvT[i];
    }
    const float* yb = y + (size_t)b * COUT * TOUT;
    for (int i = tid; i < 64 * 64; i += 256) {
        int c = i >> 6, tt = i & 63;
        int t = t0 + tt;
        y_sh[c * 72 + tt] = (t < TOUT) ? yb[c * TOUT + t] : 0.f;
    }
    __syncthreads();

    int oo = tid & 63, tq = tid >> 6;   // tq in 0..3 -> 16 t each
    float q[16], k[16], v[16];
#pragma unroll
    for (int j = 0; j < 16; j++) { q[j] = 0.f; k[j] = 0.f; v[j] = 0.f; }

#pragma unroll 1
    for (int c = 0; c < 64; ++c) {
        float wq = w_sh[c * 64 + oo];
        float wk = w_sh[4096 + c * 64 + oo];
        float wv = w_sh[8192 + c * 64 + oo];
        const float* yr = &y_sh[c * 72 + tq * 16];
#pragma unroll
        for (int j4 = 0; j4 < 4; ++j4) {
            float4 y4 = *(const float4*)(yr + 4 * j4);
            float ys[4] = {y4.x, y4.y, y4.z, y4.w};
#pragma unroll
            for (int j = 0; j < 4; ++j) {
                float yv = ys[j];
                float sp = yv > 0.f ? 1.f : 0.f;
                q[4 * j4 + j] += wq * sp;
                k[4 * j4 + j] += wk * sp;
                v[4 * j4 + j] += wv * yv;
            }
        }
    }

    int tbase = t0 + tq * 16;
#pragma unroll
    for (int j = 0; j < 16; ++j) {
        size_t off = ((size_t)b * TPAD + tbase + j) * 64 + oo;
        q_h[off] = f32_to_bf16_rne(q[j]);
        k_h[off] = f32_to_bf16_rne(k[j]);
    }
    union { unsigned short u[16]; uint4 q4[2]; } V;
#pragma unroll
    for (int j = 0; j < 16; ++j) V.u[j] = f32_to_bf16_rne(v[j]);
    unsigned short* vp = vT_h + ((size_t)b * 64 + oo) * TPAD + tbase;
    ((uint4*)vp)[0] = V.q4[0];
    ((uint4*)vp)[1] = V.q4[1];
}

// ---------------------------------------------------------------------------
// K2: MFMA attention per (b, 16-t tile), 512 threads / 8 waves.
//   (a) softmax row reductions via __shfl_xor over each 32-lane half-wave
//   (no red_sh, 2 fewer barriers); (b) exp pass packs P to bf16 IN PLACE
//   inside each row's sc_sh region (write word w=sg+32k2 is data-dependent
//   on this lane's read and disjoint from all later-iteration read words
//   64k2'..; per-row private so no cross-half-wave hazard); (c) PV reads P
//   as one ds_read_b128 per MFMA instead of 8 scalar conflicted f32 reads +
//   per-wave re-conversion.
// ---------------------------------------------------------------------------
__global__ __launch_bounds__(512, 3) void attn_kernel(
    const unsigned short* __restrict__ q_h, const unsigned short* __restrict__ k_h,
    const unsigned short* __restrict__ vT_h, const float* __restrict__ y,
    const unsigned short* __restrict__ wo_h, const unsigned short* __restrict__ wo_l,
    float* __restrict__ out)
{
    __shared__ __align__(16) float sc_sh[16 * 648];  // 41472 B (f32 scores, then bf16 P in place)
    __shared__ float ctx_sh[2 * 64 * 17];  // 8704 B (kh partials)
    __shared__ float rden[16];             // 64 B  => 50240 total -> 3 blk/CU

    int b = blockIdx.y, t0 = blockIdx.x * 16, tid = threadIdx.x;
    int wave = tid >> 6, lane = tid & 63;
    int quad = lane >> 4, nlo = lane & 15;

    // ---- scores: wave w covers s in [w*80, (w+1)*80), 5 nt steps ----
    const unsigned short* qb = q_h + ((size_t)b * TPAD + t0 + nlo) * 64 + quad * 8;
    bf16x8 qa0 = *(const bf16x8*)(qb);
    bf16x8 qa1 = *(const bf16x8*)(qb + 32);
    const unsigned short* kbase = k_h + (size_t)b * TPAD * 64 + quad * 8;
#pragma unroll 5
    for (int nt = 0; nt < 5; ++nt) {
        int s = wave * 80 + nt * 16 + nlo;
        const unsigned short* krow = kbase + (size_t)s * 64;
        bf16x8 kb0 = *(const bf16x8*)(krow);
        bf16x8 kb1 = *(const bf16x8*)(krow + 32);
        f32x4 acc = {0.f, 0.f, 0.f, 0.f};
        acc = mfma_bf16(qa0, kb0, acc);
        acc = mfma_bf16(qa1, kb1, acc);
#pragma unroll
        for (int r = 0; r < 4; ++r)
            sc_sh[(quad * 4 + r) * 648 + s] = acc[r] * 0.125f;
    }
    __syncthreads();

    // ---- softmax over s: 32 lanes/row, shfl reductions, in-place bf16 P ----
    int ti1 = tid >> 5, sg = tid & 31;
    float* srow = &sc_sh[ti1 * 648];
    float mx = -3.0e38f;
    for (int s = sg; s < TOUT; s += 32) mx = fmaxf(mx, srow[s]);
#pragma unroll
    for (int off = 16; off >= 1; off >>= 1) mx = fmaxf(mx, __shfl_xor(mx, off));

    unsigned short* prow = (unsigned short*)srow;   // row-local halves 0..1295
    float sum = 0.f;
#pragma unroll
    for (int k2 = 0; k2 < 10; ++k2) {
        int s = 2 * sg + 64 * k2;                   // even, covers 0..638
        float2 v2 = *(const float2*)(srow + s);     // ds_read_b64
        float e0 = (s     < TOUT) ? __expf(v2.x - mx) : 0.f;
        float e1 = (s + 1 < TOUT) ? __expf(v2.y - mx) : 0.f;
        sum += e0 + e1;
        unsigned u0 = __float_as_uint(e0); u0 += 0x7FFFu + ((u0 >> 16) & 1u);
        unsigned u1 = __float_as_uint(e1); u1 += 0x7FFFu + ((u1 >> 16) & 1u);
        *(unsigned*)(prow + s) = (u0 >> 16) | (u1 & 0xFFFF0000u);  // halves s, s+1
    }
#pragma unroll
    for (int off = 16; off >= 1; off >>= 1) sum += __shfl_xor(sum, off);
    if (sg == 0) rden[ti1] = 1.f / sum;
    __syncthreads();

    // ---- PV: wave -> (c-tile = (w&3)*16, K-half = w>>2); 10 ks steps ----
    int cw = (wave & 3) * 16, kh = wave >> 2;
    const unsigned short* vb = vT_h + ((size_t)b * 64 + cw + nlo) * TPAD;
    const unsigned short* pb = (const unsigned short*)sc_sh + nlo * 1296;  // P row t=nlo
    f32x4 cacc = {0.f, 0.f, 0.f, 0.f};
    int ks0 = kh * 10;
#pragma unroll 5
    for (int i = 0; i < 10; ++i) {
        int ks = ks0 + i;
        bf16x8 pv = *(const bf16x8*)(pb + ks * 32 + quad * 8);   // ds_read_b128
        bf16x8 v8 = *(const bf16x8*)(vb + ks * 32 + quad * 8);
        cacc = mfma_bf16(pv, v8, cacc);
    }
#pragma unroll
    for (int r = 0; r < 4; ++r)
        ctx_sh[kh * 1088 + (cw + nlo) * 17 + quad * 4 + r] = cacc[r] * rden[quad * 4 + r];
    __syncthreads();

    // ---- epilogue (waves 0-3): out = y + wo @ ctx, wave -> o-tile ----
    if (wave < 4) {
        const unsigned short* woh = wo_h + (size_t)(wave * 16 + nlo) * 64 + quad * 8;
        const unsigned short* wol = wo_l + (size_t)(wave * 16 + nlo) * 64 + quad * 8;
        f32x4 oacc = {0.f, 0.f, 0.f, 0.f};
#pragma unroll
        for (int ks = 0; ks < 2; ++ks) {
            union { unsigned short u[8]; bf16x8 v; } Bc;
#pragma unroll
            for (int j = 0; j < 8; ++j) {
                int c = ks * 32 + quad * 8 + j;
                float cv = ctx_sh[c * 17 + nlo] + ctx_sh[1088 + c * 17 + nlo];
                Bc.u[j] = f32_to_bf16_rne(cv);
            }
            bf16x8 ah = *(const bf16x8*)(woh + ks * 32);
            bf16x8 al = *(const bf16x8*)(wol + ks * 32);
            oacc = mfma_bf16(ah, Bc.v, oacc);
            oacc = mfma_bf16(al, Bc.v, oacc);
        }
        int t_g = t0 + nlo;
        if (t_g < TOUT) {
#pragma unroll
            for (int r = 0; r < 4; ++r) {
                int o = wave * 16 + quad * 4 + r;
                size_t off = ((size_t)b * COUT + o) * TOUT + t_g;
                out[off] = y[off] + oacc[r];
            }
        }
    }
}

// ---------------------------------------------------------------------------
extern "C" void kernel_launch(void* const* d_in, const int* in_sizes, int n_in,
                              void* d_out, int out_size, void* d_ws, size_t ws_size,
                              hipStream_t stream) {
    const float* x        = (const float*)d_in[0];
    const float* conv_w   = (const float*)d_in[1];
    const float* conv_b   = (const float*)d_in[2];
    const float* bn_gamma = (const float*)d_in[3];
    const float* bn_beta  = (const float*)d_in[4];
    const float* bn_mean  = (const float*)d_in[5];
    const float* bn_var   = (const float*)d_in[6];
    const float* wq       = (const float*)d_in[7];
    const float* wk       = (const float*)d_in[8];
    const float* wv       = (const float*)d_in[9];
    const float* wo       = (const float*)d_in[10];
    float* out = (float*)d_out;
    float* ws  = (float*)d_ws;

    // ws layout (float offsets)
    unsigned* sgn2        = (unsigned*)ws;                    // 6912 u32
    float* alpha          = ws + 110592;                      // 64
    float* scA            = ws + 110656;                      // 64
    float* scB            = ws + 110720;                      // 64
    float* wT4            = ws + 110848;                      // 3*4096 -> 123136
    unsigned short* wo_h  = (unsigned short*)(ws + 123136);   // 2048 f
    unsigned short* wo_l  = (unsigned short*)(ws + 125184);   // 2048 f -> 127232
    float* yb             = ws + 131072;                      // 5,120,000
    unsigned short* q_h   = (unsigned short*)(ws + 5251072);  // 2,621,440 f
    unsigned short* k_h   = (unsigned short*)(ws + 7872512);  // 2,621,440 f
    unsigned short* vT_h  = (unsigned short*)(ws + 10493952); // ends 13,115,392 f

    hipLaunchKernelGGL(binarize_kernel, dim3(64), dim3(256), 0, stream, conv_w, sgn2, alpha);
    hipLaunchKernelGGL(transpose_w_kernel, dim3(5), dim3(256), 0, stream,
                       wq, wk, wv, wo, conv_b, bn_gamma, bn_beta, bn_mean, bn_var, alpha,
                       wT4, wo_h, wo_l, scA, scB);
    hipLaunchKernelGGL(conv_kernel, dim3(20, 128), dim3(256), 0, stream,
                       x, sgn2, scA, scB, yb);
    hipLaunchKernelGGL(proj_kernel, dim3(10, 128), dim3(256), 0, stream,
                       yb, wT4, wT4 + 4096, wT4 + 8192, q_h, k_h, vT_h);
    hipLaunchKernelGGL(attn_kernel, dim3(40, 128), dim3(512), 0, stream,
                       q_h, k_h, vT_h, yb, wo_h, wo_l, out);
}

// Round 3
// 433.005 us; speedup vs baseline: 1.1416x; 1.1043x over previous
//
#include <hip/hip_runtime.h>
#include <math.h>

#define B_    128
#define CIN   128
#define TIN   2500
#define COUT  64
#define KW    27
#define TOUT  625
#define TPAD  640   // padded t extent for bf16 q/k/v planes
#define CTT   32    // conv t-tile
#define GROWS 152   // conv staging rows (span 4*31+27=151, pad to 152)

typedef __bf16 bf16x8 __attribute__((ext_vector_type(8)));
typedef float  f32x4  __attribute__((ext_vector_type(4)));

__device__ __forceinline__ unsigned short f32_to_bf16_rne(float v) {
    unsigned u = __float_as_uint(v);
    u += 0x7FFFu + ((u >> 16) & 1u);
    return (unsigned short)(u >> 16);
}

__device__ __forceinline__ f32x4 mfma_bf16(bf16x8 a, bf16x8 b, f32x4 c) {
    return __builtin_amdgcn_mfma_f32_16x16x32_bf16(a, b, c, 0, 0, 0);
}

// ---------------------------------------------------------------------------
// K0: alpha[o] = mean|w|; packed sign bits:
//     sgn2[(kk*4+kg)*64 + o] = u32, byte cs holds bits j for c = cs*32+kg*8+j
// ---------------------------------------------------------------------------
__global__ void binarize_kernel(const float* __restrict__ w,
                                unsigned* __restrict__ sgn2,
                                float* __restrict__ alpha_out) {
    int o = blockIdx.x, tid = threadIdx.x;
    __shared__ float red[256];
    const float* wo_ = w + (size_t)o * (CIN * KW);
    float s = 0.f;
    for (int idx = tid; idx < CIN * KW; idx += 256) s += fabsf(wo_[idx]);
    red[tid] = s;
    __syncthreads();
    for (int st = 128; st > 0; st >>= 1) {
        if (tid < st) red[tid] += red[tid + st];
        __syncthreads();
    }
    if (tid == 0) alpha_out[o] = red[0] / (float)(CIN * KW);

    for (int t = tid; t < KW * 4; t += 256) {
        int kk = t >> 2, kg = t & 3;
        unsigned u = 0;
#pragma unroll
        for (int cs = 0; cs < 4; cs++) {
#pragma unroll
            for (int j = 0; j < 8; j++) {
                int c = cs * 32 + kg * 8 + j;
                float v = wo_[c * KW + kk];
                unsigned bit = (v > 0.f) ? 0u : 1u;
                u |= bit << (cs * 8 + j);
            }
        }
        sgn2[(kk * 4 + kg) * 64 + o] = u;
    }
}

// ---------------------------------------------------------------------------
// K0b: blocks 0-2: wq/wk/wv -> bf16 hi/lo planes [o][c] (native layout);
//      block 3: wo -> bf16 hi/lo [o][c]; block 4: fold alpha+bias+BN.
// ---------------------------------------------------------------------------
__global__ void transpose_w_kernel(const float* __restrict__ wq, const float* __restrict__ wk,
                                   const float* __restrict__ wv, const float* __restrict__ wo,
                                   const float* __restrict__ conv_b, const float* __restrict__ gamma_,
                                   const float* __restrict__ beta_, const float* __restrict__ mean_,
                                   const float* __restrict__ var_, const float* __restrict__ alpha_,
                                   unsigned short* __restrict__ w3_h, unsigned short* __restrict__ w3_l,
                                   unsigned short* __restrict__ wo_h, unsigned short* __restrict__ wo_l,
                                   float* __restrict__ scA, float* __restrict__ scB) {
    if (blockIdx.x < 3) {
        const float* srcs[3] = {wq, wk, wv};
        const float* src = srcs[blockIdx.x];
        unsigned short* dh = w3_h + (size_t)blockIdx.x * 4096;
        unsigned short* dl = w3_l + (size_t)blockIdx.x * 4096;
        for (int idx = threadIdx.x; idx < 4096; idx += 256) {
            float v = src[idx];
            unsigned short h = f32_to_bf16_rne(v);
            float hf = __uint_as_float((unsigned)h << 16);
            dh[idx] = h;
            dl[idx] = f32_to_bf16_rne(v - hf);
        }
    } else if (blockIdx.x == 3) {
        for (int idx = threadIdx.x; idx < 4096; idx += 256) {
            float v = wo[idx];
            unsigned short h = f32_to_bf16_rne(v);
            float hf = __uint_as_float((unsigned)h << 16);
            wo_h[idx] = h;
            wo_l[idx] = f32_to_bf16_rne(v - hf);
        }
    } else {
        int o = threadIdx.x;
        if (o < 64) {
            float inv = rsqrtf(var_[o] + 1e-5f);
            float G = gamma_[o] * inv;
            scA[o] = alpha_[o] * G;
            scB[o] = (conv_b[o] - mean_[o]) * G + beta_[o];
        }
    }
}

// ---------------------------------------------------------------------------
// K1: binarized conv1d via bf16 MFMA + BN/ELU -> y, FUSED with the q/k/v
//   projections (the old proj kernel re-read all of y + re-staged 48KB of
//   weights per block; here the y tile is already in the block).
//   After the K-loop, y/spike are staged bf16 into LDS overlaid on the dead
//   xhi buffer (c8 XOR-swizzle -> conflict-free ds_read_b128 B-fragments);
//   each wave computes its 16-o slice of q/k/v with hi/lo-split bf16 weights
//   (spike exact in bf16 => q/k keep f32-level precision). q/k transpose
//   through LDS to coalesced 16B stores; v via a t8-swizzled [c][t] tile.
// ---------------------------------------------------------------------------
__global__ __launch_bounds__(256, 4) void conv_kernel(
    const float* __restrict__ x, const unsigned* __restrict__ sgn2,
    const float* __restrict__ scA, const float* __restrict__ scB,
    const unsigned short* __restrict__ w3_h, const unsigned short* __restrict__ w3_l,
    float* __restrict__ y_out,
    unsigned short* __restrict__ q_h, unsigned short* __restrict__ k_h,
    unsigned short* __restrict__ vT_h)
{
    __shared__ __align__(16) unsigned short xhi[GROWS * 128];  // 38912 B
    __shared__ __align__(16) unsigned long long sgnlut[16];    // 128 B
    // overlays on xhi (valid only after the post-K-loop barrier):
    unsigned short* y_sh = xhi;            // [32][64] bf16, c8-swizzled
    unsigned short* s_sh = xhi + 2048;     // spike plane, same layout
    unsigned short* q_sh = xhi + 4096;     // [32][64] bf16, o8-swizzled
    unsigned short* k_sh = xhi + 6144;
    unsigned short* v_sh = xhi + 8192;     // [64][32] bf16, t8-swizzled

    int b = blockIdx.y;
    int t0 = blockIdx.x * CTT;
    int tid = threadIdx.x;

    // ---- nibble -> 4x bf16(+-1.0) LUT (bit=1 => -1.0) ----
    if (tid < 16) {
        unsigned long long e = 0;
#pragma unroll
        for (int j = 0; j < 4; ++j) {
            unsigned long long h = ((tid >> j) & 1) ? 0xBF80ull : 0x3F80ull;
            e |= h << (16 * j);
        }
        sgnlut[tid] = e;
    }

    // ---- stage x (hi bf16, RNE): task = (c8, gl); 8 loads -> one b128 ----
    const float* xb = x + (size_t)b * CIN * TIN;
    int gbase = 4 * t0 - 13;
    for (int task = tid; task < 16 * GROWS; task += 256) {
        int c8 = task / GROWS, gl = task - c8 * GROWS;
        int g = gbase + gl;
        bool valid = (gl < 151) && ((unsigned)g < (unsigned)TIN);
        float vs[8];
#pragma unroll
        for (int j = 0; j < 8; j++)
            vs[j] = valid ? xb[(size_t)(c8 * 8 + j) * TIN + g] : 0.f;
        union { unsigned u[4]; uint4 q; } H;
#pragma unroll
        for (int j = 0; j < 4; j++) {
            unsigned short h0 = f32_to_bf16_rne(vs[2 * j]);
            unsigned short h1 = f32_to_bf16_rne(vs[2 * j + 1]);
            H.u[j] = (unsigned)h0 | ((unsigned)h1 << 16);
        }
        int c8p = c8 ^ ((gl >> 2) & 15);
        *(uint4*)(xhi + gl * 128 + c8p * 8) = H.q;
    }
    __syncthreads();

    // ---- MFMA K-loop ----
    int wave = tid >> 6, lane = tid & 63;
    int o0 = wave * 16;             // 16-o slice per wave
    int n = lane & 15, kg = lane >> 4;

    f32x4 acc0 = {0.f, 0.f, 0.f, 0.f};   // t-tile 0 (t0..t0+15)
    f32x4 acc1 = {0.f, 0.f, 0.f, 0.f};   // t-tile 1 (t0+16..t0+31)

    const unsigned* sgb = sgn2 + (size_t)kg * 64 + o0 + n;
    unsigned sa = sgb[0];

#pragma unroll 1
    for (int kk = 0; kk < KW; ++kk) {
        unsigned na = 0;
        if (kk < KW - 1) na = sgb[(kk + 1) * 256];   // prefetch (L1-hot)
        int gl = 4 * n + kk;                          // t-tile 0 row
        int rot = (gl >> 2) & 15;                     // same rot for gl+64
        const unsigned short* xr0 = xhi + gl * 128;
        const unsigned short* xr1 = xr0 + 8192;       // +64 rows
#pragma unroll
        for (int cs = 0; cs < 4; ++cs) {
            int c8p = (cs * 4 + kg) ^ rot;
            bf16x8 b0 = *(const bf16x8*)(xr0 + c8p * 8);
            bf16x8 b1 = *(const bf16x8*)(xr1 + c8p * 8);
            unsigned byte = (sa >> (8 * cs)) & 0xFFu;
            union { unsigned long long u[2]; bf16x8 v; } A;
            A.u[0] = sgnlut[byte & 15u];
            A.u[1] = sgnlut[byte >> 4];
            acc0 = mfma_bf16(A.v, b0, acc0);
            acc1 = mfma_bf16(A.v, b1, acc1);
        }
        sa = na;
    }

    // ---- epilogue: BN/ELU, y_out store, pack y+spike (pads -> 0) ----
    int quad = kg, col = n;
    unsigned long long ypk[2], spk[2];
#pragma unroll
    for (int tt = 0; tt < 2; ++tt) {
        int t_g = t0 + tt * 16 + col;
        f32x4 a = tt ? acc1 : acc0;
        unsigned long long yp = 0, sp = 0;
#pragma unroll
        for (int r = 0; r < 4; ++r) {
            int o = o0 + quad * 4 + r;
            float s = a[r] * scA[o] + scB[o];
            float yv = s > 0.f ? s : expm1f(s);
            if (t_g < TOUT) {
                y_out[((size_t)b * COUT + o) * TOUT + t_g] = yv;
                yp |= (unsigned long long)f32_to_bf16_rne(yv) << (16 * r);
                if (yv > 0.f) sp |= 0x3F80ull << (16 * r);
            }
        }
        ypk[tt] = yp; spk[tt] = sp;
    }
    __syncthreads();     // all waves done reading xhi -> overlays become valid

    int c8w = (o0 >> 3) + (quad >> 1);   // ((o0 + quad*4) >> 3)
    int cof = (quad & 1) * 4;
#pragma unroll
    for (int tt = 0; tt < 2; ++tt) {
        int tl = tt * 16 + col;
        int idx = tl * 64 + ((c8w ^ (tl & 7)) << 3) + cof;
        *(unsigned long long*)(y_sh + idx) = ypk[tt];
        *(unsigned long long*)(s_sh + idx) = spk[tt];
    }
    __syncthreads();

    // ---- fused projections: wave w -> o-rows [o0, o0+16) of q,k,v ----
    bf16x8 sf[2][2], yf[2][2];           // [tt][ks] B-fragments
#pragma unroll
    for (int tt = 0; tt < 2; ++tt)
#pragma unroll
        for (int ks = 0; ks < 2; ++ks) {
            int tl = tt * 16 + col;
            int idx = tl * 64 + (((ks * 4 + quad) ^ (tl & 7)) << 3);
            sf[tt][ks] = *(const bf16x8*)(s_sh + idx);
            yf[tt][ks] = *(const bf16x8*)(y_sh + idx);
        }
    size_t wofs = (size_t)(o0 + col) * 64 + quad * 8;
    f32x4 qa[2], ka[2], va[2];
#pragma unroll
    for (int tt = 0; tt < 2; ++tt) {
        qa[tt] = (f32x4){0.f, 0.f, 0.f, 0.f};
        ka[tt] = (f32x4){0.f, 0.f, 0.f, 0.f};
        va[tt] = (f32x4){0.f, 0.f, 0.f, 0.f};
    }
#pragma unroll
    for (int ks = 0; ks < 2; ++ks) {
        bf16x8 aqh = *(const bf16x8*)(w3_h + wofs + ks * 32);
        bf16x8 aql = *(const bf16x8*)(w3_l + wofs + ks * 32);
        bf16x8 akh = *(const bf16x8*)(w3_h + 4096 + wofs + ks * 32);
        bf16x8 akl = *(const bf16x8*)(w3_l + 4096 + wofs + ks * 32);
        bf16x8 avh = *(const bf16x8*)(w3_h + 8192 + wofs + ks * 32);
        bf16x8 avl = *(const bf16x8*)(w3_l + 8192 + wofs + ks * 32);
#pragma unroll
        for (int tt = 0; tt < 2; ++tt) {
            qa[tt] = mfma_bf16(aqh, sf[tt][ks], qa[tt]);
            qa[tt] = mfma_bf16(aql, sf[tt][ks], qa[tt]);
            ka[tt] = mfma_bf16(akh, sf[tt][ks], ka[tt]);
            ka[tt] = mfma_bf16(akl, sf[tt][ks], ka[tt]);
            va[tt] = mfma_bf16(avh, yf[tt][ks], va[tt]);
            va[tt] = mfma_bf16(avl, yf[tt][ks], va[tt]);
        }
    }
    // q/k -> LDS [t][o] (o8-swizzled, 8B packs); v -> v_sh [c][t] (t8-swz)
#pragma unroll
    for (int tt = 0; tt < 2; ++tt) {
        int tl = tt * 16 + col;
        int idx = tl * 64 + ((c8w ^ (tl & 7)) << 3) + cof;
        unsigned long long qp = 0, kp = 0;
#pragma unroll
        for (int r = 0; r < 4; ++r) {
            qp |= (unsigned long long)f32_to_bf16_rne(qa[tt][r]) << (16 * r);
            kp |= (unsigned long long)f32_to_bf16_rne(ka[tt][r]) << (16 * r);
        }
        *(unsigned long long*)(q_sh + idx) = qp;
        *(unsigned long long*)(k_sh + idx) = kp;
#pragma unroll
        for (int r = 0; r < 4; ++r) {
            int c = o0 + quad * 4 + r;
            int vidx = c * 32 + (((tt * 2 + (col >> 3)) ^ quad) << 3) + (col & 7);
            v_sh[vidx] = f32_to_bf16_rne(va[tt][r]);
        }
    }
    __syncthreads();

    // ---- cooperative coalesced stores ----
    {
        int tl = tid >> 3, seg = tid & 7;
        int idx = tl * 64 + ((seg ^ (tl & 7)) << 3);
        uint4 qv = *(const uint4*)(q_sh + idx);
        uint4 kv = *(const uint4*)(k_sh + idx);
        size_t go = ((size_t)b * TPAD + t0 + tl) * 64 + seg * 8;
        *(uint4*)(q_h + go) = qv;
        *(uint4*)(k_h + go) = kv;
        int c = tid >> 2, ts = tid & 3;
        int vidx = c * 32 + ((ts ^ ((c >> 2) & 3)) << 3);
        uint4 vv = *(const uint4*)(v_sh + vidx);
        *(uint4*)(vT_h + ((size_t)b * 64 + c) * TPAD + t0 + ts * 8) = vv;
    }
}

// ---------------------------------------------------------------------------
// K2: MFMA attention per (b, 16-t tile), 512 threads / 8 waves.
//   (a) softmax row reductions via __shfl_xor over each 32-lane half-wave;
//   (b) exp pass packs P to bf16 IN PLACE inside each row's sc_sh region;
//   (c) PV reads P as one ds_read_b128 per MFMA.
// ---------------------------------------------------------------------------
__global__ __launch_bounds__(512, 3) void attn_kernel(
    const unsigned short* __restrict__ q_h, const unsigned short* __restrict__ k_h,
    const unsigned short* __restrict__ vT_h, const float* __restrict__ y,
    const unsigned short* __restrict__ wo_h, const unsigned short* __restrict__ wo_l,
    float* __restrict__ out)
{
    __shared__ __align__(16) float sc_sh[16 * 648];  // 41472 B (f32 scores, then bf16 P in place)
    __shared__ float ctx_sh[2 * 64 * 17];  // 8704 B (kh partials)
    __shared__ float rden[16];             // 64 B  => 50240 total -> 3 blk/CU

    int b = blockIdx.y, t0 = blockIdx.x * 16, tid = threadIdx.x;
    int wave = tid >> 6, lane = tid & 63;
    int quad = lane >> 4, nlo = lane & 15;

    // ---- scores: wave w covers s in [w*80, (w+1)*80), 5 nt steps ----
    const unsigned short* qb = q_h + ((size_t)b * TPAD + t0 + nlo) * 64 + quad * 8;
    bf16x8 qa0 = *(const bf16x8*)(qb);
    bf16x8 qa1 = *(const bf16x8*)(qb + 32);
    const unsigned short* kbase = k_h + (size_t)b * TPAD * 64 + quad * 8;
#pragma unroll 5
    for (int nt = 0; nt < 5; ++nt) {
        int s = wave * 80 + nt * 16 + nlo;
        const unsigned short* krow = kbase + (size_t)s * 64;
        bf16x8 kb0 = *(const bf16x8*)(krow);
        bf16x8 kb1 = *(const bf16x8*)(krow + 32);
        f32x4 acc = {0.f, 0.f, 0.f, 0.f};
        acc = mfma_bf16(qa0, kb0, acc);
        acc = mfma_bf16(qa1, kb1, acc);
#pragma unroll
        for (int r = 0; r < 4; ++r)
            sc_sh[(quad * 4 + r) * 648 + s] = acc[r] * 0.125f;
    }
    __syncthreads();

    // ---- softmax over s: 32 lanes/row, shfl reductions, in-place bf16 P ----
    int ti1 = tid >> 5, sg = tid & 31;
    float* srow = &sc_sh[ti1 * 648];
    float mx = -3.0e38f;
    for (int s = sg; s < TOUT; s += 32) mx = fmaxf(mx, srow[s]);
#pragma unroll
    for (int off = 16; off >= 1; off >>= 1) mx = fmaxf(mx, __shfl_xor(mx, off));

    unsigned short* prow = (unsigned short*)srow;   // row-local halves 0..1295
    float sum = 0.f;
#pragma unroll
    for (int k2 = 0; k2 < 10; ++k2) {
        int s = 2 * sg + 64 * k2;                   // even, covers 0..638
        float2 v2 = *(const float2*)(srow + s);     // ds_read_b64
        float e0 = (s     < TOUT) ? __expf(v2.x - mx) : 0.f;
        float e1 = (s + 1 < TOUT) ? __expf(v2.y - mx) : 0.f;
        sum += e0 + e1;
        unsigned u0 = __float_as_uint(e0); u0 += 0x7FFFu + ((u0 >> 16) & 1u);
        unsigned u1 = __float_as_uint(e1); u1 += 0x7FFFu + ((u1 >> 16) & 1u);
        *(unsigned*)(prow + s) = (u0 >> 16) | (u1 & 0xFFFF0000u);  // halves s, s+1
    }
#pragma unroll
    for (int off = 16; off >= 1; off >>= 1) sum += __shfl_xor(sum, off);
    if (sg == 0) rden[ti1] = 1.f / sum;
    __syncthreads();

    // ---- PV: wave -> (c-tile = (w&3)*16, K-half = w>>2); 10 ks steps ----
    int cw = (wave & 3) * 16, kh = wave >> 2;
    const unsigned short* vb = vT_h + ((size_t)b * 64 + cw + nlo) * TPAD;
    const unsigned short* pb = (const unsigned short*)sc_sh + nlo * 1296;  // P row t=nlo
    f32x4 cacc = {0.f, 0.f, 0.f, 0.f};
    int ks0 = kh * 10;
#pragma unroll 5
    for (int i = 0; i < 10; ++i) {
        int ks = ks0 + i;
        bf16x8 pv = *(const bf16x8*)(pb + ks * 32 + quad * 8);   // ds_read_b128
        bf16x8 v8 = *(const bf16x8*)(vb + ks * 32 + quad * 8);
        cacc = mfma_bf16(pv, v8, cacc);
    }
#pragma unroll
    for (int r = 0; r < 4; ++r)
        ctx_sh[kh * 1088 + (cw + nlo) * 17 + quad * 4 + r] = cacc[r] * rden[quad * 4 + r];
    __syncthreads();

    // ---- epilogue (waves 0-3): out = y + wo @ ctx, wave -> o-tile ----
    if (wave < 4) {
        const unsigned short* woh = wo_h + (size_t)(wave * 16 + nlo) * 64 + quad * 8;
        const unsigned short* wol = wo_l + (size_t)(wave * 16 + nlo) * 64 + quad * 8;
        f32x4 oacc = {0.f, 0.f, 0.f, 0.f};
#pragma unroll
        for (int ks = 0; ks < 2; ++ks) {
            union { unsigned short u[8]; bf16x8 v; } Bc;
#pragma unroll
            for (int j = 0; j < 8; ++j) {
                int c = ks * 32 + quad * 8 + j;
                float cv = ctx_sh[c * 17 + nlo] + ctx_sh[1088 + c * 17 + nlo];
                Bc.u[j] = f32_to_bf16_rne(cv);
            }
            bf16x8 ah = *(const bf16x8*)(woh + ks * 32);
            bf16x8 al = *(const bf16x8*)(wol + ks * 32);
            oacc = mfma_bf16(ah, Bc.v, oacc);
            oacc = mfma_bf16(al, Bc.v, oacc);
        }
        int t_g = t0 + nlo;
        if (t_g < TOUT) {
#pragma unroll
            for (int r = 0; r < 4; ++r) {
                int o = wave * 16 + quad * 4 + r;
                size_t off = ((size_t)b * COUT + o) * TOUT + t_g;
                out[off] = y[off] + oacc[r];
            }
        }
    }
}

// ---------------------------------------------------------------------------
extern "C" void kernel_launch(void* const* d_in, const int* in_sizes, int n_in,
                              void* d_out, int out_size, void* d_ws, size_t ws_size,
                              hipStream_t stream) {
    const float* x        = (const float*)d_in[0];
    const float* conv_w   = (const float*)d_in[1];
    const float* conv_b   = (const float*)d_in[2];
    const float* bn_gamma = (const float*)d_in[3];
    const float* bn_beta  = (const float*)d_in[4];
    const float* bn_mean  = (const float*)d_in[5];
    const float* bn_var   = (const float*)d_in[6];
    const float* wq       = (const float*)d_in[7];
    const float* wk       = (const float*)d_in[8];
    const float* wv       = (const float*)d_in[9];
    const float* wo       = (const float*)d_in[10];
    float* out = (float*)d_out;
    float* ws  = (float*)d_ws;

    // ws layout (float offsets)
    unsigned* sgn2        = (unsigned*)ws;                    // 6912 u32
    float* alpha          = ws + 110592;                      // 64
    float* scA            = ws + 110656;                      // 64
    float* scB            = ws + 110720;                      // 64
    unsigned short* w3_h  = (unsigned short*)(ws + 110848);   // 12288 us = 6144 f
    unsigned short* w3_l  = (unsigned short*)(ws + 116992);   // 12288 us -> 123136
    unsigned short* wo_h  = (unsigned short*)(ws + 123136);   // 2048 f
    unsigned short* wo_l  = (unsigned short*)(ws + 125184);   // 2048 f -> 127232
    float* yb             = ws + 131072;                      // 5,120,000
    unsigned short* q_h   = (unsigned short*)(ws + 5251072);  // 2,621,440 f
    unsigned short* k_h   = (unsigned short*)(ws + 7872512);  // 2,621,440 f
    unsigned short* vT_h  = (unsigned short*)(ws + 10493952); // ends 13,115,392 f

    hipLaunchKernelGGL(binarize_kernel, dim3(64), dim3(256), 0, stream, conv_w, sgn2, alpha);
    hipLaunchKernelGGL(transpose_w_kernel, dim3(5), dim3(256), 0, stream,
                       wq, wk, wv, wo, conv_b, bn_gamma, bn_beta, bn_mean, bn_var, alpha,
                       w3_h, w3_l, wo_h, wo_l, scA, scB);
    hipLaunchKernelGGL(conv_kernel, dim3(20, 128), dim3(256), 0, stream,
                       x, sgn2, scA, scB, w3_h, w3_l, yb, q_h, k_h, vT_h);
    hipLaunchKernelGGL(attn_kernel, dim3(40, 128), dim3(512), 0, stream,
                       q_h, k_h, vT_h, yb, wo_h, wo_l, out);
}